// Round 2
// baseline (5303.876 us; speedup 1.0000x reference)
//
#include <hip/hip_runtime.h>

// ============================================================================
// BiLSTM (masked fwd + per-sequence-reversed bwd) + linear emissions + CRF
// Viterbi decode.  Round 2: fix xp_gemm staging (r<16, was r<8 -> B operand
// planes never staged -> NaN cascade). Everything else unchanged.
// ============================================================================

#define B_ 64
#define T_ 512
#define NT_ 24

typedef __attribute__((ext_vector_type(8))) short bf16x8;
typedef __attribute__((ext_vector_type(4))) float f32x4;

#define MFMA16(a, b, c) __builtin_amdgcn_mfma_f32_16x16x32_bf16(a, b, c, 0, 0, 0)

__device__ __forceinline__ unsigned short f2bf(float x) {
  unsigned u = __float_as_uint(x);
  u += 0x7FFFu + ((u >> 16) & 1u);  // round-to-nearest-even
  return (unsigned short)(u >> 16);
}
__device__ __forceinline__ float bf2f(unsigned short h) {
  return __uint_as_float(((unsigned)h) << 16);
}

// ---------------- ws layout (bytes) ----------------
#define SZ_WPL  ((size_t)8388608)                 // [dir][pl][2048][512] u16
#define O_WHH   ((size_t)0)
#define O_WIH   (O_WHH + SZ_WPL)                  // 8388608
#define O_XSPL  (O_WIH + SZ_WPL)                  // 16777216 ; X hi/lo planes
#define SZ_XSPL ((size_t)67108864)
#define O_OUTPL (O_XSPL + SZ_XSPL)                // 83886080 ; [dir][pl][b][t][h]
#define SZ_OUTPL ((size_t)134217728)
#define O_HBUF  (O_OUTPL + SZ_OUTPL)              // 218103808 ; [dir][buf][pl][64][512]
#define SZ_HBUF ((size_t)524288)
#define O_HF32  (O_HBUF + SZ_HBUF)
#define SZ_ST   ((size_t)262144)                  // [dir][64][512] f32
#define O_CF32  (O_HF32 + SZ_ST)
#define O_EMIS  (O_CF32 + SZ_ST)
#define SZ_EMIS ((size_t)3145728)                 // [64][512][24] f32
#define O_XP    (O_EMIS + SZ_EMIS)                // + Tc MiB  ([2][Tc][64][2048] f32)

// ---------------- fp32 -> bf16 hi/lo split ----------------
__global__ void split_kernel(const float* __restrict__ src,
                             unsigned short* __restrict__ hi,
                             unsigned short* __restrict__ lo, int n) {
  int i = blockIdx.x * blockDim.x + threadIdx.x;
  int stride = gridDim.x * blockDim.x;
  for (; i < n; i += stride) {
    float x = src[i];
    unsigned short h = f2bf(x);
    hi[i] = h;
    lo[i] = f2bf(x - bf2f(h));
  }
}

// ---------------- xp GEMM: xp[dir][t][b][n] = A(t,b)@W_ih^T + bias ---------
// A rows gathered (dir1 uses reversed time index). 128x128 tile, BK=64,
// bf16x2 triple product. LDS XOR-swizzled (16B chunk ^ (row&7)) -> 2-way max.
__global__ __launch_bounds__(256) void xp_gemm(
    const unsigned short* __restrict__ xpl,     // [pl][16777216]
    const unsigned short* __restrict__ wih_pl,  // [dir][pl][1048576]
    const float* __restrict__ bias_f, const float* __restrict__ bias_b,
    const int* __restrict__ length,
    float* __restrict__ xp, int t0, int Tc) {
  __shared__ char smem[65536];   // Ahi|Alo|Bhi|Blo each [128][64] bf16
  __shared__ int rowoff[128];
  const int tid = threadIdx.x;
  const int dir = blockIdx.z;
  const int m0 = blockIdx.x * 128;
  const int n0 = blockIdx.y * 128;
  if (tid < 128) {
    int m = m0 + tid;
    int tt = t0 + (m >> 6);
    int b = m & 63;
    int st = tt;
    if (dir) { st = length[b] - 1 - tt; st = st < 0 ? 0 : (st > 511 ? 511 : st); }
    rowoff[tid] = (b * 512 + st) * 512;
  }
  __syncthreads();
  const unsigned short* wih_d = wih_pl + (size_t)dir * 2097152;
  f32x4 acc[4][4];
#pragma unroll
  for (int i = 0; i < 4; ++i)
#pragma unroll
    for (int j = 0; j < 4; ++j) acc[i][j] = f32x4{0.f, 0.f, 0.f, 0.f};
  const int w = tid >> 6, l = tid & 63;
  const int wm = w & 1, wn = w >> 1;
  for (int ks = 0; ks < 8; ++ks) {
    int k0 = ks * 64;
    __syncthreads();  // protect prior reads before overwrite
#pragma unroll
    for (int r = 0; r < 16; ++r) {   // FIX: 4096 granules (was 8 -> B never staged)
      int u = tid + 256 * r;
      int plane = u >> 10;
      int rem = u & 1023;
      int row = rem >> 3, cph = rem & 7;
      int koff = k0 + (cph ^ (row & 7)) * 8;  // pre-swizzled source
      const unsigned short* src;
      if (plane < 2) src = xpl + (size_t)plane * 16777216 + rowoff[row] + koff;
      else src = wih_d + (size_t)(plane - 2) * 1048576 + (n0 + row) * 512 + koff;
      *(uint4*)(smem + u * 16) = *(const uint4*)src;  // linear LDS dest
    }
    __syncthreads();
#pragma unroll
    for (int kf = 0; kf < 2; ++kf) {
      bf16x8 ah[4], al[4], bh[4], bl[4];
#pragma unroll
      for (int x = 0; x < 4; ++x) {
        int arow = wm * 64 + x * 16 + (l & 15);
        int ac = (kf * 4 + (l >> 4)) ^ (arow & 7);
        ah[x] = *(const bf16x8*)(smem + arow * 128 + ac * 16);
        al[x] = *(const bf16x8*)(smem + 16384 + arow * 128 + ac * 16);
        int brow = wn * 64 + x * 16 + (l & 15);
        int bc = (kf * 4 + (l >> 4)) ^ (brow & 7);
        bh[x] = *(const bf16x8*)(smem + 32768 + brow * 128 + bc * 16);
        bl[x] = *(const bf16x8*)(smem + 49152 + brow * 128 + bc * 16);
      }
#pragma unroll
      for (int mi = 0; mi < 4; ++mi)
#pragma unroll
        for (int ni = 0; ni < 4; ++ni) {
          acc[mi][ni] = MFMA16(ah[mi], bh[ni], acc[mi][ni]);
          acc[mi][ni] = MFMA16(al[mi], bh[ni], acc[mi][ni]);
          acc[mi][ni] = MFMA16(ah[mi], bl[ni], acc[mi][ni]);
        }
    }
  }
  const float* bias = dir ? bias_b : bias_f;
  float* xpd = xp + (size_t)dir * (size_t)Tc * 131072;
#pragma unroll
  for (int mi = 0; mi < 4; ++mi)
#pragma unroll
    for (int ni = 0; ni < 4; ++ni)
#pragma unroll
      for (int i = 0; i < 4; ++i) {
        int m = m0 + wm * 64 + mi * 16 + (l >> 4) * 4 + i;   // C/D row (m89)
        int nn = n0 + wn * 64 + ni * 16 + (l & 15);          // C/D col
        xpd[(size_t)m * 2048 + nn] = acc[mi][ni][i] + bias[nn];
      }
}

// ---------------- one LSTM timestep (both directions) ----------------------
// 128 wgs: dir = wg>>6, slice = wg&63 owns 8 hidden units (32 W rows).
// 8 waves = (ntile 2) x (mhalf 2) x (khalf 2); A (=h) staged in 64-k chunks.
__global__ __launch_bounds__(512) void lstm_step(
    const unsigned short* __restrict__ whh_pl,  // [dir][pl][2048][512]
    unsigned short* __restrict__ hbuf,          // [dir][buf][pl][64][512]
    const float* __restrict__ xp,               // [dir][Tc][64][2048]
    const float* __restrict__ masks, const int* __restrict__ length,
    float* __restrict__ C, float* __restrict__ H,
    unsigned short* __restrict__ outpl,         // [dir][pl][b][t][h]
    int t, int tloc, int Tc) {
  __shared__ char smem[98304];  // [0,64K)=W hi/lo ; [64K,96K)=A chunks / gbuf
  const int tid = threadIdx.x;
  const int wg = blockIdx.x;
  const int dir = wg >> 6;
  const int j0 = (wg & 63) * 8;
  const int cur = t & 1;
  const unsigned short* whh_d = whh_pl + (size_t)dir * 2097152;
  // stage W slice: 4096 x 16B granules, linear LDS, pre-swizzled source
#pragma unroll
  for (int r = 0; r < 8; ++r) {
    int u = tid + 512 * r;
    int pl = u >> 11;
    int rem = u & 2047;
    int row = rem >> 6, cph = rem & 63;        // row = 8*gate + jj
    int clog = cph ^ (row & 7);
    int grow = (row >> 3) * 512 + j0 + (row & 7);
    const unsigned short* src = whh_d + (size_t)pl * 1048576 + grow * 512 + clog * 8;
    *(uint4*)(smem + u * 16) = *(const uint4*)src;
  }
  const unsigned short* hsrc = hbuf + (size_t)(dir * 2 + cur) * 65536;
  const int w = tid >> 6, l = tid & 63;
  const int n = w & 1, mh = (w >> 1) & 1, kh = w >> 2;
  f32x4 acc[2];
  acc[0] = f32x4{0.f, 0.f, 0.f, 0.f};
  acc[1] = f32x4{0.f, 0.f, 0.f, 0.f};
  const int Ab = 65536;
  for (int ci = 0; ci < 4; ++ci) {
    // stage A chunks for both k-halves, both planes: 2048 granules
#pragma unroll
    for (int r = 0; r < 4; ++r) {
      int u = tid + 512 * r;
      int plkh = u >> 9;
      int pl = plkh >> 1, khs = plkh & 1;
      int rem = u & 511;
      int b = rem >> 3, cph = rem & 7;
      int clog = cph ^ (b & 7);
      const unsigned short* src =
          hsrc + (size_t)pl * 32768 + b * 512 + khs * 256 + ci * 64 + clog * 8;
      *(uint4*)(smem + Ab + u * 16) = *(const uint4*)src;
    }
    __syncthreads();
#pragma unroll
    for (int kf = 0; kf < 2; ++kf) {
      int brow = 16 * n + (l & 15);
      int kc = kh * 32 + ci * 8 + kf * 4 + (l >> 4);
      int bph = kc ^ (brow & 7);
      bf16x8 bh = *(const bf16x8*)(smem + brow * 1024 + bph * 16);
      bf16x8 bl = *(const bf16x8*)(smem + 32768 + brow * 1024 + bph * 16);
#pragma unroll
      for (int mi = 0; mi < 2; ++mi) {
        int arow = 32 * mh + 16 * mi + (l & 15);
        int ac = (kf * 4 + (l >> 4)) ^ (arow & 7);
        bf16x8 ahv = *(const bf16x8*)(smem + Ab + (0 + kh) * 8192 + arow * 128 + ac * 16);
        bf16x8 alv = *(const bf16x8*)(smem + Ab + (2 + kh) * 8192 + arow * 128 + ac * 16);
        acc[mi] = MFMA16(ahv, bh, acc[mi]);
        acc[mi] = MFMA16(alv, bh, acc[mi]);
        acc[mi] = MFMA16(ahv, bl, acc[mi]);
      }
    }
    __syncthreads();
  }
  // reduce the two k-half partials via LDS (reuses A region)
  float* gbuf = (float*)(smem + Ab);  // [kh][64][32]
#pragma unroll
  for (int mi = 0; mi < 2; ++mi)
#pragma unroll
    for (int i = 0; i < 4; ++i) {
      int b = 32 * mh + 16 * mi + 4 * (l >> 4) + i;
      int col = 16 * n + (l & 15);
      gbuf[(kh * 64 + b) * 32 + col] = acc[mi][i];
    }
  __syncthreads();
  {  // elementwise gate update: thread -> (b, jj)
    int b = tid >> 3, jj = tid & 7;
    float g4[4];
#pragma unroll
    for (int g = 0; g < 4; ++g) {
      float v = gbuf[b * 32 + g * 8 + jj] + gbuf[(64 + b) * 32 + g * 8 + jj];
      v += xp[((size_t)dir * Tc + tloc) * 131072 + b * 2048 + g * 512 + j0 + jj];
      g4[g] = v;
    }
    float ig = 1.f / (1.f + expf(-g4[0]));
    float fg = 1.f / (1.f + expf(-g4[1]));
    float gg = tanhf(g4[2]);
    float og = 1.f / (1.f + expf(-g4[3]));
    int j = j0 + jj;
    size_t sidx = ((size_t)dir * 64 + b) * 512 + j;
    float c_old = C[sidx], h_old = H[sidx];
    float cn = fg * c_old + ig * gg;
    float hn = og * tanhf(cn);
    float m = masks[b * 512 + t];
    float cnew = (m > 0.f) ? cn : c_old;
    float hnew = (m > 0.f) ? hn : h_old;
    C[sidx] = cnew;
    H[sidx] = hnew;
    unsigned short hi = f2bf(hnew);
    unsigned short lo = f2bf(hnew - bf2f(hi));
    unsigned short* hw = hbuf + (size_t)(dir * 2 + (cur ^ 1)) * 65536;
    hw[b * 512 + j] = hi;
    hw[32768 + b * 512 + j] = lo;
    if (dir == 0) {
      size_t rb = ((size_t)b * 512 + t) * 512 + j;
      outpl[rb] = (m > 0.f) ? hi : (unsigned short)0;
      outpl[16777216 + rb] = (m > 0.f) ? lo : (unsigned short)0;
    } else if (m > 0.f) {
      int tp = length[b] - 1 - t;  // un-reverse
      size_t rb = ((size_t)b * 512 + tp) * 512 + j;
      outpl[(size_t)2 * 16777216 + rb] = hi;
      outpl[(size_t)3 * 16777216 + rb] = lo;
    }
  }
}

// ---------------- emissions: [b,t,24] = hidden(1024) . W_out^T + b_out -----
__global__ __launch_bounds__(256) void emis_kernel(
    const unsigned short* __restrict__ outpl, const float* __restrict__ Wout,
    const float* __restrict__ bout, float* __restrict__ emis) {
  __shared__ float red[64][25][4];
  int tid = threadIdx.x;
  int p = tid >> 6, rr = tid & 63;  // p = k-quarter
  int r = blockIdx.x * 64 + rr;
  int b = r >> 9, t = r & 511;
  int dir = p >> 1;
  int jq = (p & 1) * 256;
  const unsigned short* hp = outpl + (size_t)(dir * 2) * 16777216 + ((size_t)b * 512 + t) * 512 + jq;
  const unsigned short* lp = outpl + (size_t)(dir * 2 + 1) * 16777216 + ((size_t)b * 512 + t) * 512 + jq;
  float acc[24];
#pragma unroll
  for (int i = 0; i < 24; ++i) acc[i] = 0.f;
  for (int kc = 0; kc < 32; ++kc) {
    uint4 vh = *(const uint4*)(hp + kc * 8);
    uint4 vl = *(const uint4*)(lp + kc * 8);
    unsigned uh[4] = {vh.x, vh.y, vh.z, vh.w};
    unsigned ul[4] = {vl.x, vl.y, vl.z, vl.w};
    float f[8];
#pragma unroll
    for (int z = 0; z < 4; ++z) {
      f[2 * z] = bf2f((unsigned short)(uh[z] & 0xffff)) + bf2f((unsigned short)(ul[z] & 0xffff));
      f[2 * z + 1] = bf2f((unsigned short)(uh[z] >> 16)) + bf2f((unsigned short)(ul[z] >> 16));
    }
    const float* wbase = Wout + dir * 512 + jq + kc * 8;
#pragma unroll
    for (int nn = 0; nn < 24; ++nn) {
      const float* wr = wbase + nn * 1024;
      float4 w0 = *(const float4*)(wr);
      float4 w1 = *(const float4*)(wr + 4);
      acc[nn] += f[0] * w0.x + f[1] * w0.y + f[2] * w0.z + f[3] * w0.w +
                 f[4] * w1.x + f[5] * w1.y + f[6] * w1.z + f[7] * w1.w;
    }
  }
#pragma unroll
  for (int nn = 0; nn < 24; ++nn) red[rr][nn][p] = acc[nn];
  __syncthreads();
#pragma unroll
  for (int oi = 0; oi < 6; ++oi) {
    int idx = tid + 256 * oi;  // 0..1535
    int rr2 = idx / 24, n2 = idx % 24;
    float v = red[rr2][n2][0] + red[rr2][n2][1] + red[rr2][n2][2] + red[rr2][n2][3] + bout[n2];
    emis[((size_t)blockIdx.x * 64 + rr2) * 24 + n2] = v;
  }
}

// ---------------- Viterbi + backtrace: 1 wave per batch --------------------
__global__ __launch_bounds__(64) void viterbi_kernel(
    const float* __restrict__ emis, const float* __restrict__ masks,
    const int* __restrict__ length, const float* __restrict__ trans,
    float* __restrict__ out) {
  __shared__ float tr[576];
  __shared__ unsigned char bp[512 * 24];
  __shared__ unsigned char seq[512];
  int b = blockIdx.x, l = threadIdx.x;
  int lc = (l < 24) ? l : 0;
  for (int i = l; i < 576; i += 64) tr[i] = trans[i];
  __syncthreads();
  const float* eb = emis + (size_t)b * 12288;
  float alpha = (l < 24) ? eb[l] + tr[22 * 24 + l] : -3e38f;  // START row
  for (int t = 1; t < 512; ++t) {
    float mx = -3e38f;
    int arg = 0;
#pragma unroll
    for (int p = 0; p < 24; ++p) {
      float v = __shfl(alpha, p) + tr[p * 24 + lc];
      if (v > mx) { mx = v; arg = p; }  // strict > keeps first max (jnp.argmax)
    }
    if (l < 24) {
      bp[t * 24 + l] = (unsigned char)arg;
      if (masks[b * 512 + t] > 0.f) alpha = mx + eb[t * 24 + l];
    }
  }
  float fin = (l < 24) ? alpha + tr[lc * 24 + 23] : -3e38f;  // END col
  float best = -3e38f;
  int cur = 0;
  for (int p = 0; p < 24; ++p) {
    float v = __shfl(fin, p);
    if (v > best) { best = v; cur = p; }
  }
  int last = length[b] - 1;
  if (l == 0) {
    out[b] = best;
    int c = cur;
    for (int t = 511; t >= 0; --t) {
      seq[t] = (unsigned char)c;
      if (t >= 1 && t <= last) c = bp[t * 24 + c];
    }
  }
  __syncthreads();
  for (int i = l; i < 512; i += 64) out[64 + b * 512 + i] = (float)seq[i];
}

// ---------------- host ----------------
extern "C" void kernel_launch(void* const* d_in, const int* in_sizes, int n_in,
                              void* d_out, int out_size, void* d_ws, size_t ws_size,
                              hipStream_t stream) {
  const float* X = (const float*)d_in[0];
  const float* masks = (const float*)d_in[1];
  const int* length = (const int*)d_in[2];
  const float* Wih_f = (const float*)d_in[3];
  const float* Whh_f = (const float*)d_in[4];
  const float* b_f = (const float*)d_in[5];
  const float* Wih_b = (const float*)d_in[6];
  const float* Whh_b = (const float*)d_in[7];
  const float* b_b = (const float*)d_in[8];
  const float* Wout = (const float*)d_in[9];
  const float* bout = (const float*)d_in[10];
  const float* trans = (const float*)d_in[11];

  char* ws = (char*)d_ws;
  unsigned short* whh_pl = (unsigned short*)(ws + O_WHH);
  unsigned short* wih_pl = (unsigned short*)(ws + O_WIH);
  unsigned short* xspl = (unsigned short*)(ws + O_XSPL);
  unsigned short* outpl = (unsigned short*)(ws + O_OUTPL);
  unsigned short* hbuf = (unsigned short*)(ws + O_HBUF);
  float* Hbuf = (float*)(ws + O_HF32);
  float* Cbuf = (float*)(ws + O_CF32);
  float* emis = (float*)(ws + O_EMIS);
  float* xp = (float*)(ws + O_XP);

  // xp chunk length in timesteps: 1 MiB per t ([2][64][2048] f32)
  int Tc = 2;
  const int cands[9] = {512, 256, 128, 64, 32, 16, 8, 4, 2};
  for (int i = 0; i < 9; ++i) {
    if (O_XP + (size_t)cands[i] * 1048576 <= ws_size) { Tc = cands[i]; break; }
  }
  int nch = T_ / Tc;

  hipMemsetAsync(ws + O_OUTPL, 0, SZ_OUTPL, stream);
  hipMemsetAsync(ws + O_HBUF, 0, SZ_HBUF + 2 * SZ_ST, stream);  // hbuf + H + C

  split_kernel<<<2048, 256, 0, stream>>>(Whh_f, whh_pl, whh_pl + 1048576, 1048576);
  split_kernel<<<2048, 256, 0, stream>>>(Whh_b, whh_pl + 2097152, whh_pl + 3145728, 1048576);
  split_kernel<<<2048, 256, 0, stream>>>(Wih_f, wih_pl, wih_pl + 1048576, 1048576);
  split_kernel<<<2048, 256, 0, stream>>>(Wih_b, wih_pl + 2097152, wih_pl + 3145728, 1048576);
  split_kernel<<<8192, 256, 0, stream>>>(X, xspl, xspl + 16777216, 16777216);

  for (int ch = 0; ch < nch; ++ch) {
    int t0 = ch * Tc;
    xp_gemm<<<dim3(Tc * 64 / 128, 16, 2), 256, 0, stream>>>(
        xspl, wih_pl, b_f, b_b, length, xp, t0, Tc);
    for (int k = 0; k < Tc; ++k)
      lstm_step<<<128, 512, 0, stream>>>(whh_pl, hbuf, xp, masks, length, Cbuf,
                                         Hbuf, outpl, t0 + k, k, Tc);
  }
  emis_kernel<<<512, 256, 0, stream>>>(outpl, Wout, bout, emis);
  viterbi_kernel<<<64, 64, 0, stream>>>(emis, masks, length, trans, (float*)d_out);
}